// Round 2
// baseline (2842.051 us; speedup 1.0000x reference)
//
#include <hip/hip_runtime.h>
#include <hip/hip_bf16.h>

// Bidirectional LSTM, B=32 T=512 D=H=512. f32 I/O, bf16 MFMA internally.
//
// R8: per-wave decoupled cross-wg sync, grid=(32,2).
//  - flags[dir][wave][32]: producer wave w stores its 8 batches of h, drains
//    ONLY its own vmcnt, raises flag[w][s]. No whole-wg pre-signal barrier.
//  - Consumer wave w stages exactly batches [8w,8w+8) (the ones producer
//    wave w wrote) and polls only its own 32-flag quarter (one 128B line,
//    32 readers instead of 256 on one line). Barrier C (lgkm+s_barrier)
//    then collectively enforces the all-quarters AND before h-MFMAs.
//  - 2 barriers/step (C: hA/xA visible, D: vbuf ready). No vmcnt(0) full
//    drain anywhere in the loop except the per-wave 256B h-store ack.
//  - Window work (xA(t+1) stage from regs, x(t+2) prefetch, x-MFMAs) kept
//    before the poll; out-store stays after the signal.

typedef __bf16 bf16;
typedef __attribute__((ext_vector_type(8))) __bf16 bf16x8;
typedef __attribute__((ext_vector_type(4))) float f32x4;

__device__ __forceinline__ float sigmoidf_(float x) {
  return 1.f / (1.f + __expf(-x));
}
__device__ __forceinline__ float tanhf_(float x) {
  float e = __expf(-2.f * fabsf(x));
  return copysignf((1.f - e) / (1.f + e), x);
}
__device__ __forceinline__ unsigned ald(const unsigned* p) {
  return __hip_atomic_load(p, __ATOMIC_RELAXED, __HIP_MEMORY_SCOPE_AGENT);
}
__device__ __forceinline__ unsigned long long ald64(const unsigned long long* p) {
  return __hip_atomic_load(p, __ATOMIC_RELAXED, __HIP_MEMORY_SCOPE_AGENT);
}
__device__ __forceinline__ void ast(unsigned* p, unsigned v) {
  __hip_atomic_store(p, v, __ATOMIC_RELAXED, __HIP_MEMORY_SCOPE_AGENT);
}
__device__ __forceinline__ bf16x8 cvt8v(float4 a, float4 b) {
  bf16x8 v;
  v[0] = (bf16)a.x; v[1] = (bf16)a.y; v[2] = (bf16)a.z; v[3] = (bf16)a.w;
  v[4] = (bf16)b.x; v[5] = (bf16)b.y; v[6] = (bf16)b.z; v[7] = (bf16)b.w;
  return v;
}
// Barrier with LDS-visibility only: does NOT drain vmcnt, so in-flight
// global prefetches survive across it.
__device__ __forceinline__ void bar_lgkm() {
  asm volatile("s_waitcnt lgkmcnt(0)\n\ts_barrier" ::: "memory");
}

// ---------------- lengths ----------------
__global__ void lengths_kernel(const int* __restrict__ mask, int* __restrict__ lengths) {
  __shared__ int part[32][8];
  int t = threadIdx.x;
  int b = t >> 3, sub = t & 7;
  int s = 0;
#pragma unroll 8
  for (int k = 0; k < 64; ++k) s += mask[b * 512 + sub + 8 * k];
  part[b][sub] = s;
  __syncthreads();
  if (sub == 0) {
    int tot = 0;
#pragma unroll
    for (int k = 0; k < 8; ++k) tot += part[b][k];
    lengths[b] = tot;
  }
}

// ---------------- fused persistent LSTM ----------------
__global__ __launch_bounds__(256, 1) void lstm_fused(
    const float* __restrict__ x,                                  // [32][512][512] f32
    const float* __restrict__ Wih_f, const float* __restrict__ bih_f,
    const float* __restrict__ Whh_f,
    const float* __restrict__ Wih_b, const float* __restrict__ bih_b,
    const float* __restrict__ Whh_b,
    const int* __restrict__ lengths,
    unsigned* __restrict__ hbuf,        // [2 dir][2 par][32][256] dwords (2 bf16 each)
    unsigned* __restrict__ flags,       // [2][4][32] dwords: [dir][wave][wg]
    float* __restrict__ out) {          // [32][512][1024] f32
  const int s = blockIdx.x;             // h-col slice: cols [16s, 16s+16)
  const int dir = blockIdx.y;
  const float* Wih = dir ? Wih_b : Wih_f;
  const float* Whh = dir ? Whh_b : Whh_f;
  const float* bih = dir ? bih_b : bih_f;
  unsigned* flg = flags + dir * 128;

  const int tid = threadIdx.x;
  const int lane = tid & 63, wave = tid >> 6;
  const int l15 = lane & 15, quad = lane >> 4;

  __shared__ __align__(16) bf16 xA[2][32 * 512];  // 2x32 KB double buffer
  __shared__ __align__(16) bf16 hA[32 * 512];     // 32 KB
  __shared__ float vbuf[4][32][17];
  __shared__ int lenL[32];

  // Weight slices f32 -> bf16 registers (B-frag layout: k=quad*8+j, n=l15).
  bf16x8 wih[16], whh[16];
  {
    int grow = wave * 512 + s * 16 + l15;
#pragma unroll
    for (int k = 0; k < 16; ++k) {
      const float* pw = Wih + (size_t)grow * 512 + k * 32 + quad * 8;
      const float* ph = Whh + (size_t)grow * 512 + k * 32 + quad * 8;
      wih[k] = cvt8v(*(const float4*)pw, *(const float4*)(pw + 4));
      whh[k] = cvt8v(*(const float4*)ph, *(const float4*)(ph + 4));
    }
  }
  const float bv = bih[wave * 512 + s * 16 + l15];
  if (tid < 32) lenL[tid] = lengths[tid];
  __syncthreads();

  const int cb = tid >> 3, cj = (tid & 7) * 2;
  // hoist lengths into registers: per-chunk rotation bases + own-row base
  int lenR[8];
#pragma unroll
  for (int i = 0; i < 8; ++i) lenR[i] = lenL[(i * 256 + tid) >> 6];
  const int lenO = lenL[cb];

  float creg0 = 0.f, creg1 = 0.f;
  unsigned* hb = hbuf + dir * (2 * 32 * 256);

  // Prologue: load x(0), stage xA[0], then issue prefetch of x(1).
  float4 xp[8][2];
#pragma unroll
  for (int i = 0; i < 8; ++i) {
    int c = i * 256 + tid;
    int m = c >> 6, kbp = c & 63;
    int kb = kbp ^ (m & 7);
    int tr = (dir == 0) ? 0 : ((511 + lenR[i]) & 511);
    const float4* p = (const float4*)(x + ((size_t)m * 512 + tr) * 512 + kb * 8);
    xp[i][0] = p[0]; xp[i][1] = p[1];
  }
#pragma unroll
  for (int i = 0; i < 8; ++i) {
    int c = i * 256 + tid;
    *(bf16x8*)(xA[0] + c * 8) = cvt8v(xp[i][0], xp[i][1]);
  }
#pragma unroll
  for (int i = 0; i < 8; ++i) {
    int c = i * 256 + tid;
    int m = c >> 6, kbp = c & 63;
    int kb = kbp ^ (m & 7);
    int tr = (dir == 0) ? 1 : ((510 + lenR[i]) & 511);
    const float4* p = (const float4*)(x + ((size_t)m * 512 + tr) * 512 + kb * 8);
    xp[i][0] = p[0]; xp[i][1] = p[1];
  }
  bar_lgkm();  // xA[0] staged

  for (int step = 0; step < 512; ++step) {
    const int par = step & 1;
    const unsigned* hprev = hb + par * (32 * 256);
    unsigned* hnext = hb + (par ^ 1) * (32 * 256);
    const bf16* xcur = xA[par];
    bf16* xnxt = xA[par ^ 1];

    // ---- (a) window work: no dependence on incoming h(step) ----
    if (step < 511) {
#pragma unroll
      for (int i = 0; i < 8; ++i) {
        int c = i * 256 + tid;
        *(bf16x8*)(xnxt + c * 8) = cvt8v(xp[i][0], xp[i][1]);
      }
    }
    if (step < 510) {
#pragma unroll
      for (int i = 0; i < 8; ++i) {
        int c = i * 256 + tid;
        int m = c >> 6, kbp = c & 63;
        int kb = kbp ^ (m & 7);
        int tr = (dir == 0) ? (step + 2) : ((509 - step + lenR[i]) & 511);
        const float4* p = (const float4*)(x + ((size_t)m * 512 + tr) * 512 + kb * 8);
        xp[i][0] = p[0]; xp[i][1] = p[1];
      }
    }

    // x-part MFMAs: v += x@Wih^T (+bias)
    f32x4 acc0 = {bv, bv, bv, bv};
    f32x4 acc1 = {bv, bv, bv, bv};
#pragma unroll
    for (int k = 0; k < 16; ++k) {
      int kb = k * 4 + quad;
      int sw = (kb ^ (l15 & 7)) * 8;
      bf16x8 ax0 = *(const bf16x8*)(xcur + l15 * 512 + sw);
      bf16x8 ax1 = *(const bf16x8*)(xcur + (16 + l15) * 512 + sw);
      acc0 = __builtin_amdgcn_mfma_f32_16x16x32_bf16(ax0, wih[k], acc0, 0, 0, 0);
      acc1 = __builtin_amdgcn_mfma_f32_16x16x32_bf16(ax1, wih[k], acc1, 0, 0, 0);
    }
    __builtin_amdgcn_sched_barrier(0);  // pin window work before the poll

    // ---- (b) poll OWN quarter: producer wave `wave` of all 32 wgs ----
    {
      unsigned target = (unsigned)step;
      const unsigned* q = flg + wave * 32;
      bool done;
      do {
        unsigned v = (lane < 32) ? ald(q + lane) : target;
        done = __all((int)(v >= target));
        if (!done) __builtin_amdgcn_s_sleep(1);
      } while (!done);
    }

    // ---- (c) stage producer-aligned h batches [8*wave, 8*wave+8) ----
#pragma unroll
    for (int i = 0; i < 8; ++i) {
      int m = wave * 8 + i;
      int kb = lane ^ (m & 7);
      const unsigned long long* hp =
          (const unsigned long long*)(hprev + m * 256 + kb * 4);
      unsigned long long d0 = ald64(hp), d1 = ald64(hp + 1);
      int c = m * 64 + lane;
      *(unsigned long long*)(hA + c * 8) = d0;
      *(unsigned long long*)(hA + c * 8 + 4) = d1;
    }
    bar_lgkm();  // C: hA + xnxt visible; collectively = all quarters detected

    // ---- (e) h-part MFMAs: v += h@Whh^T ----
#pragma unroll
    for (int k = 0; k < 16; ++k) {
      int kb = k * 4 + quad;
      int sw = (kb ^ (l15 & 7)) * 8;
      bf16x8 ah0 = *(const bf16x8*)(hA + l15 * 512 + sw);
      bf16x8 ah1 = *(const bf16x8*)(hA + (16 + l15) * 512 + sw);
      acc0 = __builtin_amdgcn_mfma_f32_16x16x32_bf16(ah0, whh[k], acc0, 0, 0, 0);
      acc1 = __builtin_amdgcn_mfma_f32_16x16x32_bf16(ah1, whh[k], acc1, 0, 0, 0);
    }
#pragma unroll
    for (int r = 0; r < 4; ++r) {
      vbuf[wave][quad * 4 + r][l15] = acc0[r];
      vbuf[wave][16 + quad * 4 + r][l15] = acc1[r];
    }
    bar_lgkm();  // D: vbuf ready

    // ---- (g) cell update + per-wave signal ----
    float i0 = vbuf[0][cb][cj],     f0 = vbuf[1][cb][cj];
    float g0 = vbuf[2][cb][cj],     o0 = vbuf[3][cb][cj];
    float i1 = vbuf[0][cb][cj + 1], f1 = vbuf[1][cb][cj + 1];
    float g1 = vbuf[2][cb][cj + 1], o1 = vbuf[3][cb][cj + 1];
    float c0 = sigmoidf_(f0) * creg0 + sigmoidf_(i0) * tanhf_(g0);
    float c1 = sigmoidf_(f1) * creg1 + sigmoidf_(i1) * tanhf_(g1);
    creg0 = c0; creg1 = c1;
    float h0 = tanhf_(c0) * sigmoidf_(o0);
    float h1 = tanhf_(c1) * sigmoidf_(o1);
    unsigned ulo = (unsigned)__builtin_bit_cast(unsigned short, (bf16)h0);
    unsigned uhi = (unsigned)__builtin_bit_cast(unsigned short, (bf16)h1);
    // wave w stores batches [8w,8w+8): producer-aligned with consumer wave w
    ast(hnext + cb * 256 + s * 8 + (tid & 7), ulo | (uhi << 16));
    // drain ONLY this wave's stores (x prefetch long retired), then signal
    asm volatile("s_waitcnt vmcnt(0)" ::: "memory");
    if (step < 511 && lane == 0)
      ast(flg + wave * 32 + s, (unsigned)(step + 1));

    // out-store AFTER the signal (nobody consumes it)
    int tr = (dir == 0) ? step : ((511 - step + lenO) & 511);
    *(float2*)(out + (size_t)(cb * 512 + tr) * 1024 + dir * 512 + s * 16 + cj) =
        make_float2(h0, h1);
  }
}

extern "C" void kernel_launch(void* const* d_in, const int* in_sizes, int n_in,
                              void* d_out, int out_size, void* d_ws, size_t ws_size,
                              hipStream_t stream) {
  (void)in_sizes; (void)n_in; (void)out_size; (void)ws_size;
  const float* x    = (const float*)d_in[0];
  const int*   mask = (const int*)  d_in[1];
  const float* Wihf = (const float*)d_in[2];
  const float* bihf = (const float*)d_in[3];
  const float* Whhf = (const float*)d_in[4];
  const float* Wihb = (const float*)d_in[5];
  const float* bihb = (const float*)d_in[6];
  const float* Whhb = (const float*)d_in[7];
  float* out = (float*)d_out;

  char* ws = (char*)d_ws;
  unsigned* flags = (unsigned*)ws;            // [2][4][32] dwords = 1024 B
  int* lengths = (int*)(ws + 1024);           // 128 B
  unsigned* hbuf = (unsigned*)(ws + 2048);    // 131072 B
  const size_t head = 2048 + (size_t)2 * 2 * 32 * 256 * sizeof(unsigned);

  hipMemsetAsync(d_ws, 0, head, stream);      // re-arm flags + h0 = c0 = 0 every call
  lengths_kernel<<<1, 256, 0, stream>>>(mask, lengths);
  lstm_fused<<<dim3(32, 2), 256, 0, stream>>>(
      x, Wihf, bihf, Whhf, Wihb, bihb, Whhb, lengths, hbuf, flags, out);
}

// Round 3
// 2152.513 us; speedup vs baseline: 1.3203x; 1.3203x over previous
//
#include <hip/hip_runtime.h>
#include <hip/hip_bf16.h>

// Bidirectional LSTM, B=32 T=512 D=H=512. f32 I/O, bf16 MFMA internally.
//
// R9: flagless tagged-payload handoff, grid=(32,2).
//  - h exchanged as 8B atomic entries: (tag=step+1)<<32 | (2 bf16 cols).
//    Consumers poll the DATA lines (32 x 8B per lane) until all embedded
//    tags reach the step; the successful poll iteration IS the data load.
//    One LLC round-trip on the critical path instead of 3-4 (store-ack /
//    flag-store / flag-propagate / data-load of R6-R8).
//  - Producer: fire-and-forget 8B store after the cell. No vmcnt drain,
//    no flag array, no signal.
//  - 2-slot parity double buffer retained; overwrite safety: P stores h(t)
//    only after observing tag>=t on ALL entries => every wg passed barrier C
//    of step t-1 => all reads of the slot being overwritten completed.
//  - 2 intra-wg barriers/step (C: hA/xA staged, D: vbuf), lgkmcnt-only.
//  - Window work (xA(t+1) stage, x(t+2) prefetch, x-MFMAs) before the poll.

typedef __bf16 bf16;
typedef __attribute__((ext_vector_type(8))) __bf16 bf16x8;
typedef __attribute__((ext_vector_type(4))) float f32x4;
typedef unsigned long long u64;

__device__ __forceinline__ float sigmoidf_(float x) {
  return 1.f / (1.f + __expf(-x));
}
__device__ __forceinline__ float tanhf_(float x) {
  float e = __expf(-2.f * fabsf(x));
  return copysignf((1.f - e) / (1.f + e), x);
}
__device__ __forceinline__ u64 ald64(const u64* p) {
  return __hip_atomic_load(p, __ATOMIC_RELAXED, __HIP_MEMORY_SCOPE_AGENT);
}
__device__ __forceinline__ void ast64(u64* p, u64 v) {
  __hip_atomic_store(p, v, __ATOMIC_RELAXED, __HIP_MEMORY_SCOPE_AGENT);
}
__device__ __forceinline__ bf16x8 cvt8v(float4 a, float4 b) {
  bf16x8 v;
  v[0] = (bf16)a.x; v[1] = (bf16)a.y; v[2] = (bf16)a.z; v[3] = (bf16)a.w;
  v[4] = (bf16)b.x; v[5] = (bf16)b.y; v[6] = (bf16)b.z; v[7] = (bf16)b.w;
  return v;
}
// Barrier with LDS-visibility only: does NOT drain vmcnt, so in-flight
// global prefetches survive across it.
__device__ __forceinline__ void bar_lgkm() {
  asm volatile("s_waitcnt lgkmcnt(0)\n\ts_barrier" ::: "memory");
}

// ---------------- lengths ----------------
__global__ void lengths_kernel(const int* __restrict__ mask, int* __restrict__ lengths) {
  __shared__ int part[32][8];
  int t = threadIdx.x;
  int b = t >> 3, sub = t & 7;
  int s = 0;
#pragma unroll 8
  for (int k = 0; k < 64; ++k) s += mask[b * 512 + sub + 8 * k];
  part[b][sub] = s;
  __syncthreads();
  if (sub == 0) {
    int tot = 0;
#pragma unroll
    for (int k = 0; k < 8; ++k) tot += part[b][k];
    lengths[b] = tot;
  }
}

// ---------------- fused persistent LSTM ----------------
__global__ __launch_bounds__(256, 1) void lstm_fused(
    const float* __restrict__ x,                                  // [32][512][512] f32
    const float* __restrict__ Wih_f, const float* __restrict__ bih_f,
    const float* __restrict__ Whh_f,
    const float* __restrict__ Wih_b, const float* __restrict__ bih_b,
    const float* __restrict__ Whh_b,
    const int* __restrict__ lengths,
    u64* __restrict__ hbuf,             // [2 dir][2 par][32 batch][256] u64 entries
    float* __restrict__ out) {          // [32][512][1024] f32
  const int s = blockIdx.x;             // h-col slice: cols [16s, 16s+16)
  const int dir = blockIdx.y;
  const float* Wih = dir ? Wih_b : Wih_f;
  const float* Whh = dir ? Whh_b : Whh_f;
  const float* bih = dir ? bih_b : bih_f;

  const int tid = threadIdx.x;
  const int lane = tid & 63, wave = tid >> 6;
  const int l15 = lane & 15, quad = lane >> 4;

  __shared__ __align__(16) bf16 xA[2][32 * 512];  // 2x32 KB double buffer
  __shared__ __align__(16) bf16 hA[32 * 512];     // 32 KB
  __shared__ float vbuf[4][32][17];
  __shared__ int lenL[32];

  // Weight slices f32 -> bf16 registers (B-frag layout: k=quad*8+j, n=l15).
  bf16x8 wih[16], whh[16];
  {
    int grow = wave * 512 + s * 16 + l15;
#pragma unroll
    for (int k = 0; k < 16; ++k) {
      const float* pw = Wih + (size_t)grow * 512 + k * 32 + quad * 8;
      const float* ph = Whh + (size_t)grow * 512 + k * 32 + quad * 8;
      wih[k] = cvt8v(*(const float4*)pw, *(const float4*)(pw + 4));
      whh[k] = cvt8v(*(const float4*)ph, *(const float4*)(ph + 4));
    }
  }
  const float bv = bih[wave * 512 + s * 16 + l15];
  if (tid < 32) lenL[tid] = lengths[tid];
  __syncthreads();

  const int cb = tid >> 3, cj = (tid & 7) * 2;
  int lenR[8];
#pragma unroll
  for (int i = 0; i < 8; ++i) lenR[i] = lenL[(i * 256 + tid) >> 6];
  const int lenO = lenL[cb];

  float creg0 = 0.f, creg1 = 0.f;
  u64* hb = hbuf + (size_t)dir * (2 * 32 * 256);

  // Prologue: load x(0), stage xA[0], then issue prefetch of x(1).
  float4 xp[8][2];
#pragma unroll
  for (int i = 0; i < 8; ++i) {
    int c = i * 256 + tid;
    int m = c >> 6, kbp = c & 63;
    int kb = kbp ^ (m & 7);
    int tr = (dir == 0) ? 0 : ((511 + lenR[i]) & 511);
    const float4* p = (const float4*)(x + ((size_t)m * 512 + tr) * 512 + kb * 8);
    xp[i][0] = p[0]; xp[i][1] = p[1];
  }
#pragma unroll
  for (int i = 0; i < 8; ++i) {
    int c = i * 256 + tid;
    *(bf16x8*)(xA[0] + c * 8) = cvt8v(xp[i][0], xp[i][1]);
  }
#pragma unroll
  for (int i = 0; i < 8; ++i) {
    int c = i * 256 + tid;
    int m = c >> 6, kbp = c & 63;
    int kb = kbp ^ (m & 7);
    int tr = (dir == 0) ? 1 : ((510 + lenR[i]) & 511);
    const float4* p = (const float4*)(x + ((size_t)m * 512 + tr) * 512 + kb * 8);
    xp[i][0] = p[0]; xp[i][1] = p[1];
  }
  bar_lgkm();  // xA[0] staged

  for (int step = 0; step < 512; ++step) {
    const int par = step & 1;
    const u64* hprev = hb + (size_t)par * (32 * 256);
    u64* hnext = hb + (size_t)(par ^ 1) * (32 * 256);
    const bf16* xcur = xA[par];
    bf16* xnxt = xA[par ^ 1];

    // ---- (a) window work: no dependence on incoming h(step-1) ----
    if (step < 511) {
#pragma unroll
      for (int i = 0; i < 8; ++i) {
        int c = i * 256 + tid;
        *(bf16x8*)(xnxt + c * 8) = cvt8v(xp[i][0], xp[i][1]);
      }
    }
    if (step < 510) {
#pragma unroll
      for (int i = 0; i < 8; ++i) {
        int c = i * 256 + tid;
        int m = c >> 6, kbp = c & 63;
        int kb = kbp ^ (m & 7);
        int tr = (dir == 0) ? (step + 2) : ((509 - step + lenR[i]) & 511);
        const float4* p = (const float4*)(x + ((size_t)m * 512 + tr) * 512 + kb * 8);
        xp[i][0] = p[0]; xp[i][1] = p[1];
      }
    }

    // x-part MFMAs: v += x@Wih^T (+bias)
    f32x4 acc0 = {bv, bv, bv, bv};
    f32x4 acc1 = {bv, bv, bv, bv};
#pragma unroll
    for (int k = 0; k < 16; ++k) {
      int kb = k * 4 + quad;
      int sw = (kb ^ (l15 & 7)) * 8;
      bf16x8 ax0 = *(const bf16x8*)(xcur + l15 * 512 + sw);
      bf16x8 ax1 = *(const bf16x8*)(xcur + (16 + l15) * 512 + sw);
      acc0 = __builtin_amdgcn_mfma_f32_16x16x32_bf16(ax0, wih[k], acc0, 0, 0, 0);
      acc1 = __builtin_amdgcn_mfma_f32_16x16x32_bf16(ax1, wih[k], acc1, 0, 0, 0);
    }
    __builtin_amdgcn_sched_barrier(0);  // pin window work before the poll

    // ---- (b) tagged-payload poll: wave w covers batches [8w,8w+8) ----
    // entry e of batch m holds cols (2e,2e+1) | tag<<32; need tag >= step.
    u64 hv[8][4];
    {
      const unsigned target = (unsigned)step;
      bool done;
      do {
#pragma unroll
        for (int b = 0; b < 8; ++b) {
          int m = wave * 8 + b;
#pragma unroll
          for (int j = 0; j < 4; ++j)
            hv[b][j] = ald64(hprev + m * 256 + lane + 64 * j);
        }
        int ok = 1;
#pragma unroll
        for (int b = 0; b < 8; ++b)
#pragma unroll
          for (int j = 0; j < 4; ++j)
            ok &= (int)((unsigned)(hv[b][j] >> 32) >= target);
        done = __all(ok);
        if (!done) __builtin_amdgcn_s_sleep(1);
      } while (!done);
    }

    // ---- (c) stage payloads -> swizzled hA (dword = 2 cols) ----
#pragma unroll
    for (int b = 0; b < 8; ++b) {
      int m = wave * 8 + b;
#pragma unroll
      for (int j = 0; j < 4; ++j) {
        int b8 = (lane >> 2) + 16 * j;          // 8-col block of col 2*(lane+64j)
        int b8s = b8 ^ (m & 7);                 // same XOR swizzle as MFMA reads
        *(unsigned*)(hA + m * 512 + b8s * 8 + 2 * (lane & 3)) = (unsigned)hv[b][j];
      }
    }
    bar_lgkm();  // C: hA + xnxt visible

    // ---- (e) h-part MFMAs: v += h@Whh^T ----
#pragma unroll
    for (int k = 0; k < 16; ++k) {
      int kb = k * 4 + quad;
      int sw = (kb ^ (l15 & 7)) * 8;
      bf16x8 ah0 = *(const bf16x8*)(hA + l15 * 512 + sw);
      bf16x8 ah1 = *(const bf16x8*)(hA + (16 + l15) * 512 + sw);
      acc0 = __builtin_amdgcn_mfma_f32_16x16x32_bf16(ah0, whh[k], acc0, 0, 0, 0);
      acc1 = __builtin_amdgcn_mfma_f32_16x16x32_bf16(ah1, whh[k], acc1, 0, 0, 0);
    }
#pragma unroll
    for (int r = 0; r < 4; ++r) {
      vbuf[wave][quad * 4 + r][l15] = acc0[r];
      vbuf[wave][16 + quad * 4 + r][l15] = acc1[r];
    }
    bar_lgkm();  // D: vbuf ready

    // ---- (g) cell update + fire-and-forget tagged h store ----
    float i0 = vbuf[0][cb][cj],     f0 = vbuf[1][cb][cj];
    float g0 = vbuf[2][cb][cj],     o0 = vbuf[3][cb][cj];
    float i1 = vbuf[0][cb][cj + 1], f1 = vbuf[1][cb][cj + 1];
    float g1 = vbuf[2][cb][cj + 1], o1 = vbuf[3][cb][cj + 1];
    float c0 = sigmoidf_(f0) * creg0 + sigmoidf_(i0) * tanhf_(g0);
    float c1 = sigmoidf_(f1) * creg1 + sigmoidf_(i1) * tanhf_(g1);
    creg0 = c0; creg1 = c1;
    float h0 = tanhf_(c0) * sigmoidf_(o0);
    float h1 = tanhf_(c1) * sigmoidf_(o1);
    unsigned ulo = (unsigned)__builtin_bit_cast(unsigned short, (bf16)h0);
    unsigned uhi = (unsigned)__builtin_bit_cast(unsigned short, (bf16)h1);
    u64 pk = ((u64)(unsigned)(step + 1) << 32) | (u64)(ulo | (uhi << 16));
    // entry e = s*8 + (tid&7) of batch cb: cols 16s+cj, +1
    ast64(hnext + cb * 256 + s * 8 + (tid & 7), pk);

    // out-store (nobody consumes it; fire and forget)
    int tr = (dir == 0) ? step : ((511 - step + lenO) & 511);
    *(float2*)(out + (size_t)(cb * 512 + tr) * 1024 + dir * 512 + s * 16 + cj) =
        make_float2(h0, h1);
  }
}

extern "C" void kernel_launch(void* const* d_in, const int* in_sizes, int n_in,
                              void* d_out, int out_size, void* d_ws, size_t ws_size,
                              hipStream_t stream) {
  (void)in_sizes; (void)n_in; (void)out_size; (void)ws_size;
  const float* x    = (const float*)d_in[0];
  const int*   mask = (const int*)  d_in[1];
  const float* Wihf = (const float*)d_in[2];
  const float* bihf = (const float*)d_in[3];
  const float* Whhf = (const float*)d_in[4];
  const float* Wihb = (const float*)d_in[5];
  const float* bihb = (const float*)d_in[6];
  const float* Whhb = (const float*)d_in[7];
  float* out = (float*)d_out;

  char* ws = (char*)d_ws;
  u64* hbuf = (u64*)ws;                          // 2*2*32*256*8 = 262144 B
  int* lengths = (int*)(ws + 262144);            // 128 B
  const size_t head = 262144;

  hipMemsetAsync(d_ws, 0, head, stream);  // zero tags (=0) + h0 = c0 = 0 every call
  lengths_kernel<<<1, 256, 0, stream>>>(mask, lengths);
  lstm_fused<<<dim3(32, 2), 256, 0, stream>>>(
      x, Wihf, bihf, Whhf, Wihb, bihb, Whhb, lengths, hbuf, out);
}